// Round 6
// baseline (330.803 us; speedup 1.0000x reference)
//
#include <hip/hip_runtime.h>

typedef __bf16 bf16x8 __attribute__((ext_vector_type(8)));
typedef __bf16 bf16x4 __attribute__((ext_vector_type(4)));
typedef float  f32x4  __attribute__((ext_vector_type(4)));

#define EMB 512
#define NROWS 256
#define BN 64
#define NCOPY 16
// 32 * log2(e)
#define K_SCALE_LOG2E 46.16624130844683f
#define SIN_M_ 0.479425538604203f
#define PI_ 3.14159265358979323846f

__device__ __forceinline__ unsigned short f2bf(float f) {
    union { float f; unsigned u; } x; x.f = f;
    return (unsigned short)((x.u + 0x7FFFu + ((x.u >> 16) & 1u)) >> 16);
}

// XOR-swizzle on LDS byte offsets: folds row bits (10..12) and bits (8..9)
// into the 16B-slot bits (4..6). Mask depends only on bits >=8, which it does
// not modify -> involution -> bijective. Preserves 8B/16B contiguity.
// Paper-verified (GF(2) enumeration): stage ds_write_b64 spreads 64 lanes
// uniformly 4/bank (hardware minimum); MFMA ds_read_b128 spreads 8 lanes per
// 16B-slot (minimum). Conflict-free in the m136 sense.
__device__ __forceinline__ int swz(int logical) {
    return logical ^ ((((logical >> 10) & 7) ^ ((logical >> 8) & 3)) << 4);
}

// ---- K1: fused: normalize features -> bf16 A; exact f32 cos_y; zero expsum ----
__global__ void prep_kernel(const float* __restrict__ F, const int* __restrict__ labels,
                            const float* __restrict__ W,
                            unsigned short* __restrict__ Abf,
                            float* __restrict__ cos_y, float* __restrict__ expsum) {
    const int row = blockIdx.x, t = threadIdx.x;
    const int lbl = labels[row];
    float2 fv = reinterpret_cast<const float2*>(F + (size_t)row * EMB)[t];
    float2 wv = reinterpret_cast<const float2*>(W + (size_t)lbl * EMB)[t];
    float ff = fv.x * fv.x + fv.y * fv.y;
    float fw = fv.x * wv.x + fv.y * wv.y;
    float ww = wv.x * wv.x + wv.y * wv.y;
    #pragma unroll
    for (int m = 1; m < 64; m <<= 1) {
        ff += __shfl_xor(ff, m); fw += __shfl_xor(fw, m); ww += __shfl_xor(ww, m);
    }
    __shared__ float sf[4], sb[4], sc[4];
    if ((t & 63) == 0) { int w = t >> 6; sf[w] = ff; sb[w] = fw; sc[w] = ww; }
    __syncthreads();
    const float a = sf[0] + sf[1] + sf[2] + sf[3];
    const float inv = 1.f / fmaxf(sqrtf(a), 1e-12f);
    ushort2 o; o.x = f2bf(fv.x * inv); o.y = f2bf(fv.y * inv);
    reinterpret_cast<ushort2*>(Abf + (size_t)row * EMB)[t] = o;
    // zero all NCOPY shadow accumulators for this row (harness poisons ws
    // with 0xAA before every timed call; this runs before gemm_lse reads it)
    if (t < NCOPY) expsum[t * NROWS + row] = 0.f;
    if (t == 0) {
        const float b = sb[0] + sb[1] + sb[2] + sb[3];
        const float c = sc[0] + sc[1] + sc[2] + sc[3];
        const float cs = b / (fmaxf(sqrtf(a), 1e-12f) * fmaxf(sqrtf(c), 1e-12f));
        cos_y[row] = fminf(fmaxf(cs, -1.f), 1.f);
    }
}

// ---- K2: fused GEMM + per-row exp-sum over 64-class chunks ----
// 512 threads = 8 waves; wave w owns rows [w*32, w*32+32).
// NOTE: no non-temporal hints on W on purpose — W (204.8 MB) fits the 256 MB
// L3, and graph-replay steady state may serve it from Infinity Cache.
__global__ __launch_bounds__(512, 4) void gemm_lse(
    const unsigned short* __restrict__ A,  // [256][512] bf16 (normalized features)
    const float* __restrict__ W,           // [C][512] raw f32
    float* __restrict__ expsum,            // [NCOPY][256] f32, atomically accumulated
    int C) {
    __shared__ unsigned short sW[BN * EMB];   // 64KB, swizzled bf16 W-tile
    __shared__ float s_invw[BN];              // per-class 1/||w||, written in stage phase

    const int t = threadIdx.x;
    const int chunk = blockIdx.x;
    const int cls_l = t >> 3;        // 0..63 local class (8 lanes per class)
    const int slice = t & 7;         // 0..7
    const int cls_g = chunk * BN + cls_l;
    const bool valid = (cls_g < C);
    char* sWc = reinterpret_cast<char*>(sW);

    // ---- stage: f32 global -> bf16 swizzled LDS, accumulate sum-of-squares ----
    // The 8 slice-lanes of a class read one CONTIGUOUS 128B segment per iter.
    const float4* src = reinterpret_cast<const float4*>(
        W + (size_t)(valid ? cls_g : 0) * EMB);
    float ss = 0.f;
    #pragma unroll 8
    for (int i = 0; i < 16; ++i) {
        float4 v = src[i * 8 + slice];          // float offset i*32 + slice*4
        if (!valid) { v.x = 0.f; v.y = 0.f; v.z = 0.f; v.w = 0.f; }  // NaN-safety for tail chunk
        ss += v.x * v.x + v.y * v.y + v.z * v.z + v.w * v.w;
        bf16x4 p;
        p.x = (__bf16)v.x; p.y = (__bf16)v.y; p.z = (__bf16)v.z; p.w = (__bf16)v.w;
        const int logical = cls_l * (EMB * 2) + i * 64 + slice * 8;
        *reinterpret_cast<bf16x4*>(sWc + swz(logical)) = p;
    }
    ss += __shfl_xor(ss, 1);
    ss += __shfl_xor(ss, 2);
    ss += __shfl_xor(ss, 4);
    if (slice == 0) s_invw[cls_l] = valid ? 1.f / fmaxf(sqrtf(ss), 1e-12f) : 0.f;
    __syncthreads();   // covers both sW and s_invw

    // ---- MFMA: wave w -> rows [w*32, w*32+32) x 64 classes, K=512 ----
    const int wave = t >> 6;
    const int lane = t & 63;
    const int g = lane >> 4;      // k-group
    const int r16 = lane & 15;    // row (A) / class (B) within 16-block

    f32x4 acc[2][4];
    #pragma unroll
    for (int mb = 0; mb < 2; ++mb)
        #pragma unroll
        for (int nb = 0; nb < 4; ++nb) acc[mb][nb] = f32x4{0.f, 0.f, 0.f, 0.f};

    #pragma unroll 4
    for (int kk = 0; kk < EMB / 32; ++kk) {
        bf16x8 bfr[4], afr[2];
        #pragma unroll
        for (int nb = 0; nb < 4; ++nb) {
            const int logical = (nb * 16 + r16) * (EMB * 2) + kk * 64 + g * 16;
            bfr[nb] = *reinterpret_cast<const bf16x8*>(sWc + swz(logical));
        }
        #pragma unroll
        for (int mb = 0; mb < 2; ++mb) {
            const int row = wave * 32 + mb * 16 + r16;
            afr[mb] = *reinterpret_cast<const bf16x8*>(A + (size_t)row * EMB + kk * 32 + g * 8);
        }
        #pragma unroll
        for (int mb = 0; mb < 2; ++mb)
            #pragma unroll
            for (int nb = 0; nb < 4; ++nb)
                acc[mb][nb] = __builtin_amdgcn_mfma_f32_16x16x32_bf16(
                    afr[mb], bfr[nb], acc[mb][nb], 0, 0, 0);
    }

    // ---- epilogue: cos -> exp2 -> row-sum -> atomic into shadow copy ----
    // (no barrier needed: s_invw was published before the first sync)
    float* dst = expsum + (chunk & (NCOPY - 1)) * NROWS;
    float iw[4], msk[4];
    #pragma unroll
    for (int nb = 0; nb < 4; ++nb) {
        iw[nb] = s_invw[nb * 16 + r16];
        msk[nb] = ((chunk * BN + nb * 16 + r16) < C) ? 1.f : 0.f;
    }
    #pragma unroll
    for (int mb = 0; mb < 2; ++mb) {
        #pragma unroll
        for (int r = 0; r < 4; ++r) {
            float rs = 0.f;
            #pragma unroll
            for (int nb = 0; nb < 4; ++nb) {
                float cs = acc[mb][nb][r] * iw[nb];
                cs = fminf(fmaxf(cs, -1.f), 1.f);
                rs += msk[nb] * exp2f(cs * K_SCALE_LOG2E - K_SCALE_LOG2E);
            }
            rs += __shfl_xor(rs, 1);
            rs += __shfl_xor(rs, 2);
            rs += __shfl_xor(rs, 4);
            rs += __shfl_xor(rs, 8);
            if (r16 == 0) atomicAdd(&dst[wave * 32 + mb * 16 + g * 4 + r], rs);
        }
    }
}

// ---- K3: fused: quantile (order-stat 51 of 256) + margins + patch + LSE + mean ----
// jnp.quantile(d, 0.2) over 256: pos = f32(0.2)*255 rounds to exactly 51.0f
// -> frac 0 -> sorted[51]; rank-selection below reproduces it bit-exactly.
__global__ void finish_kernel(const float* __restrict__ cos_y,
                              const float* __restrict__ expsum,
                              float* __restrict__ out) {
    __shared__ float sd[NROWS];
    __shared__ float s_thr;
    __shared__ float s[4];
    const int i = threadIdx.x;
    const float cy = cos_y[i];
    const float d = 1.f - cy;
    sd[i] = d;
    __syncthreads();
    int lt = 0, eq = 0;
    for (int j = 0; j < NROWS; ++j) {
        const float dj = sd[j];
        lt += (dj < d); eq += (dj == d);
    }
    if (lt <= 51 && 51 < lt + eq) s_thr = d;   // exactly one distinct value qualifies
    __syncthreads();
    const float hard = (d >= s_thr) ? 1.f : 0.f;
    const float m = 0.5f + 0.1f * d + 0.15f * hard;
    const float cosm = cy - m * SIN_M_ - (1.f - cosf(m * PI_)) * cy;
    const float sub = exp2f(cy   * K_SCALE_LOG2E - K_SCALE_LOG2E);
    const float add = exp2f(cosm * K_SCALE_LOG2E - K_SCALE_LOG2E);
    float S = 0.f;
    #pragma unroll
    for (int c = 0; c < NCOPY; ++c) S += expsum[c * NROWS + i];
    S += add - sub;
    float term = 32.f + logf(S) - 32.f * cosm;
    #pragma unroll
    for (int mm = 1; mm < 64; mm <<= 1) term += __shfl_xor(term, mm);
    if ((i & 63) == 0) s[i >> 6] = term;
    __syncthreads();
    if (i == 0) out[0] = (s[0] + s[1] + s[2] + s[3]) * (1.f / 256.f);
}

extern "C" void kernel_launch(void* const* d_in, const int* in_sizes, int n_in,
                              void* d_out, int out_size, void* d_ws, size_t ws_size,
                              hipStream_t stream) {
    (void)n_in; (void)out_size; (void)ws_size;
    const float* F      = (const float*)d_in[0];
    const int*   labels = (const int*)d_in[1];
    const float* W      = (const float*)d_in[2];
    float* out = (float*)d_out;
    const int C = in_sizes[2] / EMB;             // 100000

    char* ws = (char*)d_ws;
    unsigned short* Abf = (unsigned short*)ws;   // 256*512*2 = 262144 B
    float* cos_y  = (float*)(ws + 262144);       // 256 f32
    float* expsum = cos_y + NROWS;               // NCOPY*256 f32

    const int nchunk = (C + BN - 1) / BN;

    hipLaunchKernelGGL(prep_kernel,   dim3(NROWS),  dim3(256), 0, stream,
                       F, labels, W, Abf, cos_y, expsum);
    hipLaunchKernelGGL(gemm_lse,      dim3(nchunk), dim3(512), 0, stream, Abf, W, expsum, C);
    hipLaunchKernelGGL(finish_kernel, dim3(1),      dim3(256), 0, stream,
                       cos_y, expsum, out);
}